// Round 7
// baseline (81.276 us; speedup 1.0000x reference)
//
#include <hip/hip_runtime.h>
#include <hip/hip_bf16.h>
#include <cstdint>

#define BATCH 8192
#define DIM   128
#define KBYTES 192         // 128 data i8 + 60 label bytes + 4 pad (K=192)
#define MARGIN 1.0f
#define SEPI   193548      // 2 * 6 * 127 * 127 label separator (int, exact)
#define SCALE  16.0f       // fp32 -> i8 quantization scale
#define INVS2  (1.0f / 256.0f)

typedef __attribute__((ext_vector_type(4))) int   int4v;
typedef __attribute__((ext_vector_type(4))) float f32x4;

// ---------------------------------------------------------------------------
// Kernel 1: quantize fp32 -> i8 (scale 16, clamp +-127) into label-AUGMENTED
// matrices. Row (192 B): [128 data i8][60 aug: label lab -> bytes 6*lab..
// 6*lab+5 = +127 (A) / -127 (B)][4 zero pad]. dot_aug = dot - 96774*[same];
// val = sqj - 2*dot_aug = (sqj - 2*dot) + 193548*[same] -> pure max/min
// epilogue in EXACT i32 (everything < 2^24, float conversion exact).
// ---------------------------------------------------------------------------
__global__ __launch_bounds__(256) void bhtl_prep(
    const float* __restrict__ emb,
    const int* __restrict__ labels,
    signed char* __restrict__ EA,
    signed char* __restrict__ EB,
    int* __restrict__ sq,
    unsigned* __restrict__ hp2,
    unsigned* __restrict__ hn2)
{
    const int hw  = threadIdx.x >> 5;          // half-wave 0..7
    const int l   = threadIdx.x & 31;
    const int row = blockIdx.x * 8 + hw;
    const float4 e = ((const float4*)(emb + (size_t)row * DIM))[l];

    int a0 = (int)rintf(e.x * SCALE); a0 = min(127, max(-127, a0));
    int a1 = (int)rintf(e.y * SCALE); a1 = min(127, max(-127, a1));
    int a2 = (int)rintf(e.z * SCALE); a2 = min(127, max(-127, a2));
    int a3 = (int)rintf(e.w * SCALE); a3 = min(127, max(-127, a3));
    unsigned pa = (a0 & 255) | ((a1 & 255) << 8) | ((a2 & 255) << 16) | ((a3 & 255) << 24);
    *(unsigned*)(EA + (size_t)row * KBYTES + l * 4) = pa;
    *(unsigned*)(EB + (size_t)row * KBYTES + l * 4) = pa;   // data identical

    if (l < 16) {   // aug bytes 128..191: 4 bytes per lane
        const int lab = labels[row];
        unsigned wa = 0, wb = 0;
        #pragma unroll
        for (int b = 0; b < 4; ++b) {
            int j = l * 4 + b;                 // 0..63
            int in = (j < 60) && (j / 6 == lab);
            wa |= (unsigned)((in ?  127 : 0) & 255) << (8 * b);
            wb |= (unsigned)((in ? -127 : 0) & 255) << (8 * b);
        }
        *(unsigned*)(EA + (size_t)row * KBYTES + 128 + l * 4) = wa;
        *(unsigned*)(EB + (size_t)row * KBYTES + 128 + l * 4) = wb;
    }

    int s = a0 * a0 + a1 * a1 + a2 * a2 + a3 * a3;
    #pragma unroll
    for (int d = 1; d < 32; d <<= 1) s += __shfl_xor(s, d, 64);  // half-wave
    if (l == 0) {
        sq[row]  = s;
        hp2[row] = 0u;           // float-bits max accumulator (non-negative)
        hn2[row] = 0x7F800000u;  // +inf (min accumulator)
    }
}

// ---------------------------------------------------------------------------
// Kernel 2: fused i8 E_A @ E_B^T + int max/min epilogue, LDS-FREE.
// R6 post-mortem: VALU cuts (R6) and occupancy x2 (R2) both no-ops ->
// main is LDS-PIPE bound: the B tile made a write-24KB + read-32KB LDS
// round-trip per CU-iter with ZERO reuse (each staged byte read by exactly
// one lane once) ~= 250-320 cy at the LDS port rate vs 244 cy/iter
// measured: ~100% saturated. The LDS was only a format shim.
// FIX: lane(q,ln)'s B fragment for chunk ch, slice kc is the contiguous
// 16 B at EB[(jbase+ch*16+ln)*192 + (kc*4+q)*16] -> load it DIRECTLY into
// VGPRs. 3-deep register pipeline bq[3][3] (depth-2 prefetch, same shape
// as the proven schedule); sqj loaded directly too. NO LDS, NO barriers,
// NO global_load_lds, NO manual waitcnt: loads write VGPRs, so the
// compiler inserts exact counted vmcnt(N) waits at first use (kills the
// whole R1-class of manual-vmcnt races). Same L2 traffic, minus LDS leg.
//   2048 blocks x 64 threads; wave = 64 rows x 512 cols, 32 chunks of 16.
//   Slot rotation: consume slot ch%3, prefetch ch+2 into (ch+2)%3 (that
//   slot was consumed at ch-1: WAR safe under in-order issue). Loads for
//   ch issued at ch-2 -> ~2 iters of slack >= L1/L2 latency.
//   MFMA: mfma_i32_16x16x64_i8, transposed (acc = mfma(B, A)): lane(q,ln)
//   elem r -> row = rowbase+m*16+ln, col = jb+q*4+r. Frag bytes identical
//   to the LDS version -> semantics unchanged.
// Epilogue (R6 CUT2/3): w = 2*acc - sqj; max val = -min w, min val =
//   -max w; |w| <= 6.4M < 2^24 exact. Balanced min/max trees.
// ---------------------------------------------------------------------------
__global__ __launch_bounds__(64) void bhtl_main(
    const signed char* __restrict__ EA,
    const signed char* __restrict__ EB,
    const int* __restrict__ sq,
    unsigned* __restrict__ hp2,
    unsigned* __restrict__ hn2)
{
    const int lane = threadIdx.x;              // 0..63
    const int q    = lane >> 4;
    const int ln   = lane & 15;
    const int rb   = blockIdx.x >> 4;          // 0..127 row band (64 rows)
    const int js   = blockIdx.x & 15;          // 0..15 col split (512 cols)
    const int rowbase = rb * 64;
    const int jbase   = js * 512;

    // ---- A fragments (64 rows, K=192) pinned: 4 m x 3 kc x 4 VGPR = 48 ----
    int4v af[4][3];
    #pragma unroll
    for (int m = 0; m < 4; ++m)
        #pragma unroll
        for (int kc = 0; kc < 3; ++kc) {
            af[m][kc] = *(const int4v*)(
                EA + (size_t)(rowbase + m * 16 + ln) * KBYTES + kc * 64 + q * 16);
            asm("" : "+v"(af[m][kc]));
        }

    // ---- per-lane B base: col jbase+ln, k-offset q*16; +3072 B per chunk --
    const signed char* pB  = EB + (size_t)(jbase + ln) * KBYTES + q * 16;
    const int*         psq = sq + jbase + q * 4;   // 16 cols' sq per chunk

    // ---- 3-slot register pipeline: B frags (36 VGPR) + col sq (12) ----
    int4v bq[3][3];
    int4v sv[3];

    auto loadChunk = [&](int slot, int ch) {
        const signed char* p = pB + (size_t)ch * (16 * KBYTES);
        #pragma unroll
        for (int kc = 0; kc < 3; ++kc)
            bq[slot][kc] = *(const int4v*)(p + kc * 64);
        sv[slot] = *(const int4v*)(psq + ch * 16);
    };

    loadChunk(0, 0);
    loadChunk(1, 1);

    // w = 2*acc - sqj = -val; wmn tracks min w (-> max val), wmx max w.
    int wmn[4] = {INT_MAX, INT_MAX, INT_MAX, INT_MAX};
    int wmx[4] = {INT_MIN, INT_MIN, INT_MIN, INT_MIN};

    auto doIter = [&](int ch, int slot, bool doPf, int pfSlot) {
        if (doPf) loadChunk(pfSlot, ch + 2);   // issue before MFMA: hides latency

        // MFMA: 4 row-blocks x K=192 (3 x 16x16x64 i8); compiler inserts
        // the counted vmcnt wait for bq[slot]'s loads (issued at ch-2).
        int4v acc[4];
        const int4v zero = {0, 0, 0, 0};
        #pragma unroll
        for (int m = 0; m < 4; ++m) acc[m] = zero;
        #pragma unroll
        for (int kc = 0; kc < 3; ++kc)
            #pragma unroll
            for (int m = 0; m < 4; ++m)
                acc[m] = __builtin_amdgcn_mfma_i32_16x16x64_i8(
                    bq[slot][kc], af[m][kc], acc[m], 0, 0, 0);   // transposed

        const int4v sqj = sv[slot];
        const int nsq0 = -sqj[0], nsq1 = -sqj[1], nsq2 = -sqj[2], nsq3 = -sqj[3];
        #pragma unroll
        for (int m = 0; m < 4; ++m) {
            int w0 = acc[m][0] * 2 + nsq0;
            int w1 = acc[m][1] * 2 + nsq1;
            int w2 = acc[m][2] * 2 + nsq2;
            int w3 = acc[m][3] * 2 + nsq3;
            wmn[m] = min(wmn[m], min(min(w0, w1), min(w2, w3)));
            wmx[m] = max(wmx[m], max(max(w0, w1), max(w2, w3)));
        }
    };

    #pragma unroll 1
    for (int base = 0; base < 30; base += 3) {
        doIter(base,     0, true,          2);
        doIter(base + 1, 1, true,          0);
        doIter(base + 2, 2, base + 2 < 30, 1);
    }
    doIter(30, 0, false, 0);
    doIter(31, 1, false, 0);

    // ---- reduce over the 4 q-lanes sharing each row, then atomics ----
    // max val = -wmin, min val = -wmax:
    //   hp key = sqi + maxval - SEPI = sqi - wmin - SEPI
    //   hn key = sqi + minval        = sqi - wmax
    #pragma unroll
    for (int m = 0; m < 4; ++m) {
        int a = wmn[m], b = wmx[m];
        a = min(a, __shfl_xor(a, 16, 64));
        a = min(a, __shfl_xor(a, 32, 64));
        b = max(b, __shfl_xor(b, 16, 64));
        b = max(b, __shfl_xor(b, 32, 64));
        if (q == 0) {
            const int row = rowbase + m * 16 + ln;
            const int sqi = sq[row];
            // ints < 2^24 -> float conversion exact; clamp>=0 keeps uint
            // order == float order; splits w/o same-class col self-correct.
            float hpf = fmaxf((float)(sqi - a - SEPI) * INVS2, 0.0f);
            float hnf = fmaxf((float)(sqi - b) * INVS2, 0.0f);
            atomicMax(&hp2[row], __float_as_uint(hpf));
            atomicMin(&hn2[row], __float_as_uint(hnf));
        }
    }
}

// ---------------------------------------------------------------------------
// Kernel 3: per-anchor loss + mean. Single block, deterministic output.
// ---------------------------------------------------------------------------
__global__ __launch_bounds__(1024) void bhtl_final(
    const unsigned* __restrict__ hp2,
    const unsigned* __restrict__ hn2,
    float* __restrict__ out)
{
    __shared__ float red[16];
    float sum = 0.f;
    for (int i = threadIdx.x; i < BATCH; i += 1024) {
        float hp = sqrtf(__uint_as_float(hp2[i]));
        float hn = sqrtf(__uint_as_float(hn2[i]));
        sum += fmaxf(hp - hn + MARGIN, 0.f);
    }
    #pragma unroll
    for (int d = 1; d < 64; d <<= 1) sum += __shfl_xor(sum, d, 64);
    int wv = threadIdx.x >> 6;
    if ((threadIdx.x & 63) == 0) red[wv] = sum;
    __syncthreads();
    if (threadIdx.x < 64) {
        float v = (threadIdx.x < 16) ? red[threadIdx.x] : 0.f;
        #pragma unroll
        for (int d = 1; d < 16; d <<= 1) v += __shfl_xor(v, d, 64);
        if (threadIdx.x == 0) out[0] = v / (float)BATCH;
    }
}

// ---------------------------------------------------------------------------
extern "C" void kernel_launch(void* const* d_in, const int* in_sizes, int n_in,
                              void* d_out, int out_size, void* d_ws, size_t ws_size,
                              hipStream_t stream)
{
    const float* emb    = (const float*)d_in[0];
    const int*   labels = (const int*)d_in[1];
    float*       out    = (float*)d_out;

    char* ws = (char*)d_ws;
    signed char* EA  = (signed char*)ws;                              // 1.5 MiB
    signed char* EB  = (signed char*)(ws + 2 * 1024 * 1024);          // 1.5 MiB
    int*      sq   = (int*)     (ws + 4 * 1024 * 1024);               // 32 KiB
    unsigned* hp2  = (unsigned*)(ws + 4 * 1024 * 1024 + 32 * 1024);   // 32 KiB
    unsigned* hn2  = (unsigned*)(ws + 4 * 1024 * 1024 + 64 * 1024);   // 32 KiB

    bhtl_prep<<<BATCH / 8, 256, 0, stream>>>(emb, labels, EA, EB, sq, hp2, hn2);
    bhtl_main<<<2048, 64, 0, stream>>>(EA, EB, sq, hp2, hn2);
    bhtl_final<<<1, 1024, 0, stream>>>(hp2, hn2, out);
}